// Round 7
// baseline (33492.996 us; speedup 1.0000x reference)
//
#include <hip/hip_runtime.h>
#include <math.h>

#define RSV   2048
#define NIN   8
#define TT    16384
#define NB    256
#define TB    512
#define RPB   8           // rows per block = waves per block
#define OUTW  (RSV+NIN)   // 2056

typedef unsigned long long u64;

// ws layout: buf0 = ws[0..2048) u64, buf1 = ws[2048..4096) u64 (32 KiB)
// word = (stamp << 32) | float_bits

__global__ __launch_bounds__(256) void esn_init(const float* __restrict__ h0,
                                                u64* __restrict__ ws) {
    int i = blockIdx.x * blockDim.x + threadIdx.x;
    if (i < RSV) {
        u64 w0 = (u64)__float_as_uint(h0[i]);   // buf0: stamp 0 | h0 payload
        __hip_atomic_store(ws + i,       w0,   __ATOMIC_RELAXED, __HIP_MEMORY_SCOPE_AGENT);
        __hip_atomic_store(ws + RSV + i, 0ull, __ATOMIC_RELAXED, __HIP_MEMORY_SCOPE_AGENT);
    }
}

__device__ __forceinline__ float tanh_fast(float s) {
    return 1.0f - 2.0f / (__expf(2.0f * s) + 1.0f);
}

__global__ __launch_bounds__(TB, 2) void esn_main(const float* __restrict__ x,
                                                  const float* __restrict__ h0,
                                                  const float* __restrict__ Win,
                                                  const float* __restrict__ Wh,
                                                  float* __restrict__ out,
                                                  u64* __restrict__ ws) {
    __shared__ __align__(16) float wh_lds[RPB * RSV];   // 64 KB: this block's 8 Wh rows
    __shared__ __align__(16) float h_lds[2][RSV];       // 16 KB: double-buffered h stage

    const int tid  = threadIdx.x;
    const int b    = blockIdx.x;
    const int wave = tid >> 6;
    const int lane = tid & 63;

    u64* buf0 = ws;
    u64* buf1 = ws + RSV;

    // ---- one-time: this block's 8 rows of Wh -> LDS (float4-coalesced, 8 iters) ----
    {
        const float4* s4 = (const float4*)(Wh + (size_t)(b * RPB) * RSV);
        float4* d4 = (float4*)wh_lds;
        #pragma unroll
        for (int i = 0; i < (RPB * RSV / 4) / TB; ++i)
            d4[tid + i * TB] = s4[tid + i * TB];
    }

    const int row = (b << 3) + wave;                 // wave owns one full row
    const float* wrow = wh_lds + wave * RSV;
    float hp = (lane == 0) ? h0[row] : 0.f;
    __syncthreads();   // wh_lds ready

    #pragma unroll 1
    for (int t = 1; t <= TT; ++t) {
        const u64* src = (t & 1) ? buf0 : buf1;   // holds h_{t-1} (stamps t-1)
        u64*       dst = (t & 1) ? buf1 : buf0;   // receives h_t (stamps t)
        float*     hl  = h_lds[t & 1];
        const unsigned want = (unsigned)(t - 1);

        // ---- h-independent work first (hidden under the poll) ----
        float winx = 0.f;
        if (lane == 0) {
            const float4* wr4 = (const float4*)(Win + row * NIN);   // L1-hot 32 B
            const float4* xr4 = (const float4*)(x + (size_t)(t - 1) * NIN);
            float4 wa = wr4[0], wb = wr4[1];
            float4 xa = xr4[0], xb = xr4[1];
            winx = wa.x*xa.x + wa.y*xa.y + wa.z*xa.z + wa.w*xa.w
                 + wb.x*xb.x + wb.y*xb.y + wb.z*xb.z + wb.w*xb.w;
        }
        if (b == 0 && wave == 0 && lane >= 8 && lane < 8 + NIN)
            out[(size_t)(t - 1) * OUTW + RSV + (lane - 8)] = x[(size_t)(t - 1) * NIN + (lane - 8)];

        // ---- poll OWN 4 stamped words (block collectively covers all 2048).
        //      Payload rides the same 8B word: consumption completes at poll-pass. ----
        const u64* sp = src + tid * 4;
        u64 v0, v1, v2, v3;
        for (;;) {
            v0 = __hip_atomic_load(sp + 0, __ATOMIC_RELAXED, __HIP_MEMORY_SCOPE_AGENT);
            v1 = __hip_atomic_load(sp + 1, __ATOMIC_RELAXED, __HIP_MEMORY_SCOPE_AGENT);
            v2 = __hip_atomic_load(sp + 2, __ATOMIC_RELAXED, __HIP_MEMORY_SCOPE_AGENT);
            v3 = __hip_atomic_load(sp + 3, __ATOMIC_RELAXED, __HIP_MEMORY_SCOPE_AGENT);
            if ((unsigned)(v0 >> 32) >= want && (unsigned)(v1 >> 32) >= want &&
                (unsigned)(v2 >> 32) >= want && (unsigned)(v3 >> 32) >= want) break;
        }
        float4 hv4;
        hv4.x = __uint_as_float((unsigned)v0);
        hv4.y = __uint_as_float((unsigned)v1);
        hv4.z = __uint_as_float((unsigned)v2);
        hv4.w = __uint_as_float((unsigned)v3);
        *(float4*)&hl[tid * 4] = hv4;
        __syncthreads();   // the ONLY barrier per step (LDS dbuf => WAR-safe)

        // ---- full-row matvec from LDS weights + LDS h.
        //      Both streams at index lane+64j: bank = lane%32, 2 lanes/bank = free. ----
        float acc = 0.f;
        #pragma unroll
        for (int j = 0; j < 32; ++j)
            acc += wrow[lane + 64 * j] * hl[lane + 64 * j];

        // ---- 64-lane butterfly -> row sum in lane 0 ----
        #pragma unroll
        for (int m = 32; m >= 1; m >>= 1)
            acc += __shfl_xor(acc, m);

        // ---- lane 0 finalizes its row; stamp store first (unblocks the grid) ----
        if (lane == 0) {
            float s  = acc + winx;
            float ht = 0.9f * hp + 0.1f * tanh_fast(s);
            hp = ht;
            u64 pk = ((u64)(unsigned)t << 32) | (u64)__float_as_uint(ht);
            __hip_atomic_store(dst + row, pk, __ATOMIC_RELAXED, __HIP_MEMORY_SCOPE_AGENT);
            out[(size_t)(t - 1) * OUTW + row] = ht;
        }
    }
}

extern "C" void kernel_launch(void* const* d_in, const int* in_sizes, int n_in,
                              void* d_out, int out_size, void* d_ws, size_t ws_size,
                              hipStream_t stream) {
    const float* x   = (const float*)d_in[0];
    const float* h0  = (const float*)d_in[1];
    const float* Win = (const float*)d_in[2];
    const float* Wh  = (const float*)d_in[3];
    float* out = (float*)d_out;
    u64*   ws  = (u64*)d_ws;

    hipLaunchKernelGGL(esn_init, dim3(8), dim3(256), 0, stream, h0, ws);
    hipLaunchKernelGGL(esn_main, dim3(NB), dim3(TB), 0, stream,
                       x, h0, Win, Wh, out, ws);
}

// Round 8
// 28239.899 us; speedup vs baseline: 1.1860x; 1.1860x over previous
//
#include <hip/hip_runtime.h>
#include <math.h>

#define RSV   2048
#define NIN   8
#define TT    16384
#define NB    128
#define TB    512
#define RPB   16          // rows per block (8 waves x 2 rows)
#define OUTW  (RSV+NIN)   // 2056

typedef unsigned long long u64;

// ws layout: buf0 = ws[0..2048) u64, buf1 = ws[2048..4096) u64 (32 KiB)
// word = (stamp << 32) | float_bits

__global__ __launch_bounds__(256) void esn_init(const float* __restrict__ h0,
                                                u64* __restrict__ ws) {
    int i = blockIdx.x * blockDim.x + threadIdx.x;
    if (i < RSV) {
        u64 w0 = (u64)__float_as_uint(h0[i]);   // buf0: stamp 0 | h0 payload
        __hip_atomic_store(ws + i,       w0,   __ATOMIC_RELAXED, __HIP_MEMORY_SCOPE_AGENT);
        __hip_atomic_store(ws + RSV + i, 0ull, __ATOMIC_RELAXED, __HIP_MEMORY_SCOPE_AGENT);
    }
}

__device__ __forceinline__ float tanh_fast(float s) {
    return 1.0f - 2.0f / (__expf(2.0f * s) + 1.0f);
}

__global__ __launch_bounds__(TB, 2) void esn_main(const float* __restrict__ x,
                                                  const float* __restrict__ h0,
                                                  const float* __restrict__ Win,
                                                  const float* __restrict__ Wh,
                                                  float* __restrict__ out,
                                                  u64* __restrict__ ws) {
    __shared__ __align__(16) float h_lds[2][RSV];   // double-buffered h stage (16 KB)

    const int tid  = threadIdx.x;
    const int b    = blockIdx.x;
    const int wave = tid >> 6;
    const int lane = tid & 63;

    u64* buf0 = ws;
    u64* buf1 = ws + RSV;

    // ---- wave owns rows row0, row0+1; lane owns cols {lane + 64j}, j=0..31.
    //      Loads have loop-invariant addresses: the compiler issues them inside
    //      the t-loop overlapped with the poll window (R6-verified behavior). ----
    const int row0 = b * RPB + wave * 2;
    float wh0[32], wh1[32];
    {
        const float* wr0 = Wh + (size_t)(row0 + 0) * RSV + lane;
        const float* wr1 = Wh + (size_t)(row0 + 1) * RSV + lane;
        #pragma unroll
        for (int j = 0; j < 32; ++j) wh0[j] = wr0[64 * j];
        #pragma unroll
        for (int j = 0; j < 32; ++j) wh1[j] = wr1[64 * j];
    }

    const int frow = row0 + (lane & 1);   // finalize lanes 0,1 own one row each
    float hp = (lane < 2) ? h0[frow] : 0.f;

    #pragma unroll 1
    for (int t = 1; t <= TT; ++t) {
        const u64* src = (t & 1) ? buf0 : buf1;   // holds h_{t-1} (stamps t-1)
        u64*       dst = (t & 1) ? buf1 : buf0;   // receives h_t (stamps t)
        float*     hl  = h_lds[t & 1];
        const unsigned want = (unsigned)(t - 1);

        // ---- h-independent work first (hidden under the poll) ----
        float winx = 0.f;
        if (lane < 2) {
            const float4* wr4 = (const float4*)(Win + frow * NIN);   // L1-hot 32 B
            const float4* xr4 = (const float4*)(x + (size_t)(t - 1) * NIN);
            float4 wa = wr4[0], wb = wr4[1];
            float4 xa = xr4[0], xb = xr4[1];
            winx = wa.x*xa.x + wa.y*xa.y + wa.z*xa.z + wa.w*xa.w
                 + wb.x*xb.x + wb.y*xb.y + wb.z*xb.z + wb.w*xb.w;
        }
        if (b == 0 && wave == 0 && lane >= 8 && lane < 8 + NIN)
            out[(size_t)(t - 1) * OUTW + RSV + (lane - 8)] = x[(size_t)(t - 1) * NIN + (lane - 8)];

        // ---- poll OWN 4 stamped words; s_sleep throttle on miss keeps the
        //      MALL uncontended (spin BW was ~14 TB/s at NB=256 w/o sleep) ----
        const u64* sp = src + tid * 4;
        u64 v0, v1, v2, v3;
        for (;;) {
            v0 = __hip_atomic_load(sp + 0, __ATOMIC_RELAXED, __HIP_MEMORY_SCOPE_AGENT);
            v1 = __hip_atomic_load(sp + 1, __ATOMIC_RELAXED, __HIP_MEMORY_SCOPE_AGENT);
            v2 = __hip_atomic_load(sp + 2, __ATOMIC_RELAXED, __HIP_MEMORY_SCOPE_AGENT);
            v3 = __hip_atomic_load(sp + 3, __ATOMIC_RELAXED, __HIP_MEMORY_SCOPE_AGENT);
            if ((unsigned)(v0 >> 32) >= want && (unsigned)(v1 >> 32) >= want &&
                (unsigned)(v2 >> 32) >= want && (unsigned)(v3 >> 32) >= want) break;
            __builtin_amdgcn_s_sleep(1);
        }
        float4 hv4;
        hv4.x = __uint_as_float((unsigned)v0);
        hv4.y = __uint_as_float((unsigned)v1);
        hv4.z = __uint_as_float((unsigned)v2);
        hv4.w = __uint_as_float((unsigned)v3);
        *(float4*)&hl[tid * 4] = hv4;
        __syncthreads();   // the ONLY barrier per step (LDS dbuf => WAR-safe)

        // ---- 2-row matvec: conflict-free LDS reads, weights from registers/L2 ----
        float px = 0.f, py = 0.f;
        #pragma unroll
        for (int j = 0; j < 32; ++j) {
            float hval = hl[lane + 64 * j];
            px += wh0[j] * hval;
            py += wh1[j] * hval;
        }

        // ---- packed butterfly: 6 shuffles for both rows ----
        float q = (lane & 1) ? py : px;
        float r = (lane & 1) ? px : py;
        q += __shfl_xor(r, 1);
        #pragma unroll
        for (int m = 2; m <= 32; m <<= 1)
            q += __shfl_xor(q, m);             // lane0: sum row0, lane1: sum row0+1

        // ---- finalize lanes; stamp store first (unblocks the grid) ----
        if (lane < 2) {
            float s  = q + winx;
            float ht = 0.9f * hp + 0.1f * tanh_fast(s);
            hp = ht;
            u64 pk = ((u64)(unsigned)t << 32) | (u64)__float_as_uint(ht);
            __hip_atomic_store(dst + frow, pk, __ATOMIC_RELAXED, __HIP_MEMORY_SCOPE_AGENT);
            out[(size_t)(t - 1) * OUTW + frow] = ht;
        }
    }
}

extern "C" void kernel_launch(void* const* d_in, const int* in_sizes, int n_in,
                              void* d_out, int out_size, void* d_ws, size_t ws_size,
                              hipStream_t stream) {
    const float* x   = (const float*)d_in[0];
    const float* h0  = (const float*)d_in[1];
    const float* Win = (const float*)d_in[2];
    const float* Wh  = (const float*)d_in[3];
    float* out = (float*)d_out;
    u64*   ws  = (u64*)d_ws;

    hipLaunchKernelGGL(esn_init, dim3(8), dim3(256), 0, stream, h0, ws);
    hipLaunchKernelGGL(esn_main, dim3(NB), dim3(TB), 0, stream,
                       x, h0, Win, Wh, out, ws);
}